// Round 7
// baseline (366.556 us; speedup 1.0000x reference)
//
#include <hip/hip_runtime.h>
#include <hip/hip_bf16.h>

// Problem: B=32, T=256, I=128, H=128, C=100. All fp32.
// out = (h_T + attn_c_final) @ w_fc.T + b_fc; only the LAST step's attention
// matters (scan carry overwrites attn_c each step).

#define Bsz 32
#define Tsz 256
#define Isz 128
#define Hsz 128
#define Csz 100
#define G4H 512   // 4*H

typedef float v2f __attribute__((ext_vector_type(2)));
typedef float v4f __attribute__((ext_vector_type(4)));

// ---------------- device helpers ----------------
// sum across the 4 lanes of a quad via DPP quad_perm (VALU pipe, no LDS)
__device__ __forceinline__ float quad_rsum(float x) {
    int t = __builtin_amdgcn_update_dpp(0, __float_as_int(x), 0xB1, 0xF, 0xF, true); // xor 1
    x += __int_as_float(t);
    t = __builtin_amdgcn_update_dpp(0, __float_as_int(x), 0x4E, 0xF, 0xF, true);     // xor 2
    x += __int_as_float(t);
    return x;
}
__device__ __forceinline__ float rcpf(float x) { return __builtin_amdgcn_rcpf(x); }
__device__ __forceinline__ float sigm_n(float x) { return rcpf(1.0f + __expf(-x)); }
__device__ __forceinline__ float tanh_n(float x) {
    float ax = fabsf(x);
    float e = __expf(-2.0f * ax);
    float t = (1.0f - e) * rcpf(1.0f + e);
    return copysignf(t, x);
}
__device__ __forceinline__ float tanh_s(float x) { return tanh_n(x); }

// ---------------- kernel 0: prep ----------------
// wih_t: (K=128, 512) for gemm1. bias = b_ih + b_hh.
// whh_pk: packed for lstm_seq; dest idx bit fields:
//   [1:0]=j4, [3:2]=q, [10:4]=d, [12:11]=gi, [15:13]=kk4
//   source k = q*32 + kk4*4 + j4, source row j = gi*128 + d  (w_hh is (4H,H))
__global__ __launch_bounds__(256) void prep_kernel(
    const float* __restrict__ w_ih, const float* __restrict__ b_ih,
    const float* __restrict__ w_hh, const float* __restrict__ b_hh,
    float* __restrict__ wih_t, float* __restrict__ whh_pk, float* __restrict__ bias) {
    int idx = blockIdx.x * blockDim.x + threadIdx.x;   // 0..65535
    if (idx < G4H * Isz) {
        int j = idx >> 7;
        int k = idx & 127;
        wih_t[k * G4H + j] = w_ih[idx];

        int j4  = idx & 3;
        int q   = (idx >> 2) & 3;
        int d   = (idx >> 4) & 127;
        int gi  = (idx >> 11) & 3;
        int kk4 = (idx >> 13) & 7;
        whh_pk[idx] = w_hh[(size_t)((gi << 7) + d) * 128 + (q << 5) + (kk4 << 2) + j4];
    }
    if (idx < G4H) bias[idx] = b_ih[idx] + b_hh[idx];
}

// ---------------- gemm128: C[M,N] = A[M,K] @ B[K,N] (+bias[N]) ----------------
#define GBK 16
#define GLD 132

__global__ __launch_bounds__(256) void gemm128(
    const float* __restrict__ A, const float* __restrict__ Bm,
    const float* __restrict__ bias, float* __restrict__ C,
    int M, int N, int K) {
    __shared__ float As[GBK][GLD];
    __shared__ float Bs[GBK][GLD];
    const int tid = threadIdx.x;
    const int bm = blockIdx.y * 128;
    const int bn = blockIdx.x * 128;
    const int tx = tid & 15, ty = tid >> 4;
    float acc[8][8] = {};

    const int ar = tid >> 2;
    const int ac = (tid & 3) * 4;
    const int br = tid >> 5;
    const int bc = (tid & 31) * 4;

    for (int k0 = 0; k0 < K; k0 += GBK) {
        #pragma unroll
        for (int h = 0; h < 2; ++h) {
            int r = ar + 64 * h;
            float4 v = *(const float4*)(A + (size_t)(bm + r) * K + k0 + ac);
            As[ac + 0][r] = v.x;
            As[ac + 1][r] = v.y;
            As[ac + 2][r] = v.z;
            As[ac + 3][r] = v.w;
        }
        #pragma unroll
        for (int h = 0; h < 2; ++h) {
            int kr = br + 8 * h;
            float4 v = *(const float4*)(Bm + (size_t)(k0 + kr) * N + bn + bc);
            *(float4*)&Bs[kr][bc] = v;
        }
        __syncthreads();
        #pragma unroll
        for (int kk = 0; kk < GBK; ++kk) {
            float a[8], b[8];
            *(float4*)&a[0] = *(const float4*)&As[kk][ty * 8];
            *(float4*)&a[4] = *(const float4*)&As[kk][ty * 8 + 4];
            *(float4*)&b[0] = *(const float4*)&Bs[kk][tx * 8];
            *(float4*)&b[4] = *(const float4*)&Bs[kk][tx * 8 + 4];
            #pragma unroll
            for (int i = 0; i < 8; ++i)
                #pragma unroll
                for (int j = 0; j < 8; ++j)
                    acc[i][j] = fmaf(a[i], b[j], acc[i][j]);
        }
        __syncthreads();
    }
    float bb[8];
    #pragma unroll
    for (int j = 0; j < 8; ++j) bb[j] = bias ? bias[bn + tx * 8 + j] : 0.0f;
    #pragma unroll
    for (int i = 0; i < 8; ++i) {
        int row = bm + ty * 8 + i;
        float4 v0, v1;
        v0.x = acc[i][0] + bb[0]; v0.y = acc[i][1] + bb[1];
        v0.z = acc[i][2] + bb[2]; v0.w = acc[i][3] + bb[3];
        v1.x = acc[i][4] + bb[4]; v1.y = acc[i][5] + bb[5];
        v1.z = acc[i][6] + bb[6]; v1.w = acc[i][7] + bb[7];
        *(float4*)(C + (size_t)row * N + bn + tx * 8) = v0;
        *(float4*)(C + (size_t)row * N + bn + tx * 8 + 4) = v1;
    }
}

// ---------------- kernel 2: sequential LSTM recurrence, one WG per batch ----------------
// R3 structure (512 thr, (d,q) layout, weights in 128 VGPRs, one barrier/step).
// FMA via native v2f + __builtin_elementwise_fma -> compiler-selected
// v_pk_fma_f32 with proper 64-bit pair allocation (no inline-asm operand
// copies, which were ~half the VALU issue in R3-R6).
#define HPAD(k) ((k) + 8 * ((k) >> 5))

__global__ __launch_bounds__(512, 2) void lstm_seq(
    const float* __restrict__ G, const float* __restrict__ whh_pk,
    float* __restrict__ H_all) {
    const int b = blockIdx.x;
    const int tid = threadIdx.x;
    const int d = tid >> 2;
    const int q = tid & 3;

    __shared__ float h_s[2][160];

    // one-time coalesced weight load, stored as native v2f pairs
    v2f w2v[4][16];
    {
        const v4f* wp = (const v4f*)whh_pk;
        #pragma unroll
        for (int kk4 = 0; kk4 < 8; ++kk4)
            #pragma unroll
            for (int gi = 0; gi < 4; ++gi) {
                v4f v = wp[((kk4 * 4 + gi) * 128 + d) * 4 + q];
                w2v[gi][kk4 * 2]     = v.xy;
                w2v[gi][kk4 * 2 + 1] = v.zw;
            }
    }

    if (tid < 320) ((float*)h_s)[tid] = 0.0f;
    float c = 0.0f;
    __syncthreads();

    const float* Gq = G + (size_t)b * Tsz * G4H + q * 128 + d;
    float* Hst = H_all + (size_t)b * Tsz * Hsz + d;   // q==0 lanes store

    float gval = Gq[0];
    int cur = 0;
    for (int t = 0; t < Tsz; ++t) {
        const int tn = (t < Tsz - 1) ? t + 1 : t;
        float ngval = Gq[(size_t)tn * G4H];   // prefetch, independent of h

        v2f accA[4], accB[4];
        #pragma unroll
        for (int gi = 0; gi < 4; ++gi) {
            accA[gi] = (v2f){q == gi ? gval : 0.f, 0.f};
            accB[gi] = (v2f){0.f, 0.f};
        }
        const float* hb = &h_s[cur][q * 40];   // HPAD(q*32)=q*40, 16B aligned
        #pragma unroll
        for (int kk4 = 0; kk4 < 8; ++kk4) {
            v4f h4 = *(const v4f*)(hb + 4 * kk4);
            v2f hA = h4.xy;
            v2f hB = h4.zw;
            accA[0] = __builtin_elementwise_fma(hA, w2v[0][2 * kk4], accA[0]);
            accA[1] = __builtin_elementwise_fma(hA, w2v[1][2 * kk4], accA[1]);
            accA[2] = __builtin_elementwise_fma(hA, w2v[2][2 * kk4], accA[2]);
            accA[3] = __builtin_elementwise_fma(hA, w2v[3][2 * kk4], accA[3]);
            accB[0] = __builtin_elementwise_fma(hB, w2v[0][2 * kk4 + 1], accB[0]);
            accB[1] = __builtin_elementwise_fma(hB, w2v[1][2 * kk4 + 1], accB[1]);
            accB[2] = __builtin_elementwise_fma(hB, w2v[2][2 * kk4 + 1], accB[2]);
            accB[3] = __builtin_elementwise_fma(hB, w2v[3][2 * kk4 + 1], accB[3]);
        }
        float a0 = quad_rsum(accA[0].x + accA[0].y + accB[0].x + accB[0].y);
        float a1 = quad_rsum(accA[1].x + accA[1].y + accB[1].x + accB[1].y);
        float a2 = quad_rsum(accA[2].x + accA[2].y + accB[2].x + accB[2].y);
        float a3 = quad_rsum(accA[3].x + accA[3].y + accB[3].x + accB[3].y);

        float iv = sigm_n(a0);
        float fv = sigm_n(a1);
        float gv = tanh_n(a2);
        float ov = sigm_n(a3);
        c = fv * c + iv * gv;
        float h = ov * tanh_n(c);

        if (q == 0) {
            h_s[cur ^ 1][HPAD(d)] = h;
            Hst[(size_t)t * Hsz] = h;
        }
        gval = ngval;
        __syncthreads();
        cur ^= 1;
    }
}

// ---------------- kernel 3: final attention + FC, one WG per batch ----------------
__global__ __launch_bounds__(256) void attn_out(
    const float* __restrict__ H_all, const float* __restrict__ KV,
    const float* __restrict__ w1, const float* __restrict__ w2,
    const float* __restrict__ w_fc, const float* __restrict__ b_fc,
    float* __restrict__ out) {
    int b = blockIdx.x;
    int tid = threadIdx.x;
    __shared__ float hT[Hsz];
    __shared__ float q_s[Hsz];
    __shared__ float w2s[Hsz];
    __shared__ float s_s[Tsz];
    __shared__ float r2[2][Hsz];
    __shared__ float r_s[Hsz];

    const float* Hb = H_all + (size_t)b * Tsz * Hsz;
    const float* KVb = KV + (size_t)b * Tsz * Hsz;

    if (tid < Hsz) {
        hT[tid] = Hb[255 * Hsz + tid];
        w2s[tid] = w2[tid];
    }
    __syncthreads();
    if (tid < Hsz) {
        float acc = 0.f;
        #pragma unroll 8
        for (int k = 0; k < Hsz; ++k) acc = fmaf(hT[k], w1[k * Hsz + tid], acc);
        q_s[tid] = acc;
    }
    __syncthreads();

    const int qd = tid >> 2, ql = tid & 3;
    #pragma unroll
    for (int jj = 0; jj < 4; ++jj) {
        int j = qd + jj * 64;
        float p = 0.f;
        if (j < 255) {
            const float* kv = KVb + (size_t)j * Hsz + ql * 32;
            const float* qs = q_s + ql * 32;
            const float* wv = w2s + ql * 32;
            #pragma unroll 8
            for (int k = 0; k < 32; ++k)
                p = fmaf(tanh_s(qs[k] + kv[k]), wv[k], p);
        }
        p = quad_rsum(p);
        if (ql == 0 && j < 255) s_s[j] = p;
    }
    __syncthreads();

    {
        int dd = tid & 127, half = tid >> 7;
        int j0 = half * 128, je = half ? 255 : 128;
        float acc = 0.f;
        #pragma unroll 4
        for (int j = j0; j < je; ++j) acc = fmaf(s_s[j], Hb[(size_t)j * Hsz + dd], acc);
        r2[half][dd] = acc;
    }
    __syncthreads();
    if (tid < Hsz) r_s[tid] = hT[tid] + r2[0][tid] + r2[1][tid];
    __syncthreads();

    {
        int o = tid >> 1, half = tid & 1;
        float acc = 0.f;
        if (o < Csz) {
            const float* wr = w_fc + (size_t)o * Hsz + half * 64;
            const float* rr = r_s + half * 64;
            #pragma unroll 8
            for (int k = 0; k < 64; ++k) acc = fmaf(rr[k], wr[k], acc);
        }
        acc += __shfl_xor(acc, 1);
        if (half == 0 && o < Csz) out[b * Csz + o] = acc + b_fc[o];
    }
}

// ---------------- launch ----------------
extern "C" void kernel_launch(void* const* d_in, const int* in_sizes, int n_in,
                              void* d_out, int out_size, void* d_ws, size_t ws_size,
                              hipStream_t stream) {
    const float* x    = (const float*)d_in[0];
    const float* w_ih = (const float*)d_in[1];
    const float* b_ih = (const float*)d_in[2];
    const float* w_hh = (const float*)d_in[3];
    const float* b_hh = (const float*)d_in[4];
    const float* w1   = (const float*)d_in[5];
    const float* w2   = (const float*)d_in[6];
    const float* w_fc = (const float*)d_in[7];
    const float* b_fc = (const float*)d_in[8];

    float* ws = (float*)d_ws;
    float* wih_t  = ws;                      // 128*512
    float* whh_pk = wih_t + 65536;           // 128*512 (packed lstm layout)
    float* bias   = whh_pk + 65536;          // 512
    float* G      = bias + 512;              // 8192*512
    float* H_all  = G + 4194304;             // 32*256*128
    float* KV     = H_all + 1048576;         // 32*256*128

    prep_kernel<<<256, 256, 0, stream>>>(w_ih, b_ih, w_hh, b_hh, wih_t, whh_pk, bias);

    dim3 g1(G4H / 128, (Bsz * Tsz) / 128);   // (4, 64)
    gemm128<<<g1, 256, 0, stream>>>(x, wih_t, bias, G, Bsz * Tsz, G4H, Isz);

    lstm_seq<<<Bsz, 512, 0, stream>>>(G, whh_pk, H_all);

    dim3 g2(Hsz / 128, (Bsz * Tsz) / 128);   // (1, 64)
    gemm128<<<g2, 256, 0, stream>>>(H_all, w1 + Hsz * Hsz, nullptr, KV, Bsz * Tsz, Hsz, Hsz);

    attn_out<<<Bsz, 256, 0, stream>>>(H_all, KV, w1, w2, w_fc, b_fc, (float*)d_out);
}

// Round 8
// 340.784 us; speedup vs baseline: 1.0756x; 1.0756x over previous
//
#include <hip/hip_runtime.h>
#include <hip/hip_bf16.h>

// Problem: B=32, T=256, I=128, H=128, C=100. All fp32.
// out = (h_T + attn_c_final) @ w_fc.T + b_fc; only the LAST step's attention
// matters (scan carry overwrites attn_c each step).

#define Bsz 32
#define Tsz 256
#define Isz 128
#define Hsz 128
#define Csz 100
#define G4H 512   // 4*H

typedef short v8s __attribute__((ext_vector_type(8)));   // 8 bf16 = 4 VGPRs
typedef float v4fa __attribute__((ext_vector_type(4)));  // MFMA acc

// ---------------- device helpers ----------------
__device__ __forceinline__ float2 pk_fma(float2 a, float2 b, float2 c) {
    float2 d;
    asm("v_pk_fma_f32 %0, %1, %2, %3" : "=v"(d) : "v"(a), "v"(b), "v"(c));
    return d;
}
__device__ __forceinline__ float quad_rsum(float x) {
    int t = __builtin_amdgcn_update_dpp(0, __float_as_int(x), 0xB1, 0xF, 0xF, true); // xor 1
    x += __int_as_float(t);
    t = __builtin_amdgcn_update_dpp(0, __float_as_int(x), 0x4E, 0xF, 0xF, true);     // xor 2
    x += __int_as_float(t);
    return x;
}
__device__ __forceinline__ float rcpf(float x) { return __builtin_amdgcn_rcpf(x); }
__device__ __forceinline__ float sigm_n(float x) { return rcpf(1.0f + __expf(-x)); }
__device__ __forceinline__ float tanh_n(float x) {
    float ax = fabsf(x);
    float e = __expf(-2.0f * ax);
    float t = (1.0f - e) * rcpf(1.0f + e);
    return copysignf(t, x);
}
__device__ __forceinline__ float tanh_s(float x) { return tanh_n(x); }

// ---------------- kernel 0: weight prep ----------------
// whh_pk: packed for lstm (as before). bias = b_ih + b_hh.
// W2ih[n][k'] (512 x 384 bf16): [w_hi | w_lo | w_hi]  (pairs with A=[hi|hi|lo])
// W2v [n][k'] (128 x 384 bf16): transpose-split of w1 bottom half.
__global__ __launch_bounds__(256) void prep_kernel(
    const float* __restrict__ w_ih, const float* __restrict__ b_ih,
    const float* __restrict__ w_hh, const float* __restrict__ b_hh,
    const float* __restrict__ w1,
    __hip_bfloat16* __restrict__ W2ih, __hip_bfloat16* __restrict__ W2v,
    float* __restrict__ whh_pk, float* __restrict__ bias) {
    int idx = blockIdx.x * blockDim.x + threadIdx.x;   // 0..65535
    if (idx < G4H * Isz) {
        int n = idx >> 7;
        int k = idx & 127;
        float x = w_ih[idx];
        __hip_bfloat16 hi = __float2bfloat16(x);
        __hip_bfloat16 lo = __float2bfloat16(x - __bfloat162float(hi));
        W2ih[(size_t)n * 384 + k] = hi;
        W2ih[(size_t)n * 384 + 128 + k] = lo;
        W2ih[(size_t)n * 384 + 256 + k] = hi;

        int j4  = idx & 3;
        int q   = (idx >> 2) & 3;
        int d   = (idx >> 4) & 127;
        int gi  = (idx >> 11) & 3;
        int kk4 = (idx >> 13) & 7;
        whh_pk[idx] = w_hh[(size_t)((gi << 7) + d) * 128 + (q << 5) + (kk4 << 2) + j4];
    }
    if (idx < Hsz * Hsz) {
        int n = idx >> 7;          // 0..127 output col of KV
        int k = idx & 127;         // inner
        float x = w1[(size_t)(128 + k) * Hsz + n];
        __hip_bfloat16 hi = __float2bfloat16(x);
        __hip_bfloat16 lo = __float2bfloat16(x - __bfloat162float(hi));
        W2v[(size_t)n * 384 + k] = hi;
        W2v[(size_t)n * 384 + 128 + k] = lo;
        W2v[(size_t)n * 384 + 256 + k] = hi;
    }
    if (idx < G4H) bias[idx] = b_ih[idx] + b_hh[idx];
}

// ---------------- split256: fp32 [M][128] -> bf16 [M][256] = [hi | lo] ----------------
__global__ __launch_bounds__(256) void split256(
    const float* __restrict__ src, __hip_bfloat16* __restrict__ dst, int total) {
    int i = blockIdx.x * 256 + threadIdx.x;
    if (i >= total) return;
    int m = i >> 7, k = i & 127;
    float x = src[i];
    __hip_bfloat16 hi = __float2bfloat16(x);
    dst[(size_t)m * 256 + k] = hi;
    dst[(size_t)m * 256 + 128 + k] = __float2bfloat16(x - __bfloat162float(hi));
}

// ---------------- gemm_mfma: C[M,N] = split(A) @ split(W)^T (+bias) ----------------
// A2: [M][256] bf16 = [a_hi | a_lo]; W2: [N][384] bf16 = [w_hi | w_lo | w_hi].
// 12 k-steps of 32; A-block mapping [hi,hi,lo] via index (hi reused) gives
// hi*hi + hi*lo + lo*hi  (~2^-17 rel error vs fp32).
// Block = 256 thr = 4 waves; each wave computes a 32x32 C tile (2x2 MFMA frags).
__global__ __launch_bounds__(256) void gemm_mfma(
    const __hip_bfloat16* __restrict__ A2, const __hip_bfloat16* __restrict__ W2,
    const float* __restrict__ bias, float* __restrict__ C, int M, int N) {
    const int tid = threadIdx.x;
    const int w = tid >> 6, lane = tid & 63;
    const int m0 = blockIdx.y * 64 + (w & 1) * 32;
    const int n0 = blockIdx.x * 64 + (w >> 1) * 32;
    const int r = lane & 15, quad = lane >> 4;

    v4fa acc[2][2] = {};
    const short* Ab = (const short*)A2;
    const short* Wb = (const short*)W2;

    #pragma unroll
    for (int ks = 0; ks < 12; ++ks) {
        int ka = (ks & 3) * 32 + ((ks >= 8) ? 128 : 0) + quad * 8;
        int kb = ks * 32 + quad * 8;
        v8s a0 = *(const v8s*)(Ab + (size_t)(m0 + r) * 256 + ka);
        v8s a1 = *(const v8s*)(Ab + (size_t)(m0 + 16 + r) * 256 + ka);
        v8s b0 = *(const v8s*)(Wb + (size_t)(n0 + r) * 384 + kb);
        v8s b1 = *(const v8s*)(Wb + (size_t)(n0 + 16 + r) * 384 + kb);
        acc[0][0] = __builtin_amdgcn_mfma_f32_16x16x32_bf16(a0, b0, acc[0][0], 0, 0, 0);
        acc[0][1] = __builtin_amdgcn_mfma_f32_16x16x32_bf16(a0, b1, acc[0][1], 0, 0, 0);
        acc[1][0] = __builtin_amdgcn_mfma_f32_16x16x32_bf16(a1, b0, acc[1][0], 0, 0, 0);
        acc[1][1] = __builtin_amdgcn_mfma_f32_16x16x32_bf16(a1, b1, acc[1][1], 0, 0, 0);
    }
    // C/D layout: col = lane&15, row = quad*4 + reg  [verified m89/m91]
    #pragma unroll
    for (int i = 0; i < 2; ++i)
        #pragma unroll
        for (int j = 0; j < 2; ++j) {
            int cn = n0 + 16 * j + r;
            float bb = bias ? bias[cn] : 0.0f;
            #pragma unroll
            for (int rr = 0; rr < 4; ++rr) {
                int row = m0 + 16 * i + quad * 4 + rr;
                C[(size_t)row * N + cn] = acc[i][j][rr] + bb;
            }
        }
}

// ---------------- kernel 2: sequential LSTM (best measured: R3, 190.7 us) ----------------
#define HPAD(k) ((k) + 8 * ((k) >> 5))

__global__ __launch_bounds__(512, 2) void lstm_seq(
    const float* __restrict__ G, const float* __restrict__ whh_pk,
    float* __restrict__ H_all) {
    const int b = blockIdx.x;
    const int tid = threadIdx.x;
    const int d = tid >> 2;
    const int q = tid & 3;

    __shared__ float h_s[2][160];

    float2 w2v[4][16];
    {
        const float4* wp = (const float4*)whh_pk;
        #pragma unroll
        for (int kk4 = 0; kk4 < 8; ++kk4)
            #pragma unroll
            for (int gi = 0; gi < 4; ++gi) {
                float4 v = wp[((kk4 * 4 + gi) * 128 + d) * 4 + q];
                w2v[gi][kk4 * 2]     = make_float2(v.x, v.y);
                w2v[gi][kk4 * 2 + 1] = make_float2(v.z, v.w);
            }
    }

    if (tid < 320) ((float*)h_s)[tid] = 0.0f;
    float c = 0.0f;
    __syncthreads();

    const float* Gq = G + (size_t)b * Tsz * G4H + q * 128 + d;
    float* Hst = H_all + (size_t)b * Tsz * Hsz + d;

    float gval = Gq[0];
    int cur = 0;
    for (int t = 0; t < Tsz; ++t) {
        const int tn = (t < Tsz - 1) ? t + 1 : t;
        float ngval = Gq[(size_t)tn * G4H];   // prefetch, independent of h

        float2 accA[4], accB[4];
        #pragma unroll
        for (int gi = 0; gi < 4; ++gi) {
            accA[gi] = make_float2(q == gi ? gval : 0.f, 0.f);
            accB[gi] = make_float2(0.f, 0.f);
        }
        const float4* hb4 = (const float4*)&h_s[cur][q * 40];  // HPAD(q*32)=q*40
        #pragma unroll
        for (int kk4 = 0; kk4 < 8; ++kk4) {
            float4 h4 = hb4[kk4];
            float2 hA = make_float2(h4.x, h4.y);
            float2 hB = make_float2(h4.z, h4.w);
            accA[0] = pk_fma(hA, w2v[0][2 * kk4], accA[0]);
            accA[1] = pk_fma(hA, w2v[1][2 * kk4], accA[1]);
            accA[2] = pk_fma(hA, w2v[2][2 * kk4], accA[2]);
            accA[3] = pk_fma(hA, w2v[3][2 * kk4], accA[3]);
            accB[0] = pk_fma(hB, w2v[0][2 * kk4 + 1], accB[0]);
            accB[1] = pk_fma(hB, w2v[1][2 * kk4 + 1], accB[1]);
            accB[2] = pk_fma(hB, w2v[2][2 * kk4 + 1], accB[2]);
            accB[3] = pk_fma(hB, w2v[3][2 * kk4 + 1], accB[3]);
        }
        float a0 = quad_rsum(accA[0].x + accA[0].y + accB[0].x + accB[0].y);
        float a1 = quad_rsum(accA[1].x + accA[1].y + accB[1].x + accB[1].y);
        float a2 = quad_rsum(accA[2].x + accA[2].y + accB[2].x + accB[2].y);
        float a3 = quad_rsum(accA[3].x + accA[3].y + accB[3].x + accB[3].y);

        float iv = sigm_n(a0);
        float fv = sigm_n(a1);
        float gv = tanh_n(a2);
        float ov = sigm_n(a3);
        c = fv * c + iv * gv;
        float h = ov * tanh_n(c);

        if (q == 0) {
            h_s[cur ^ 1][HPAD(d)] = h;
            Hst[(size_t)t * Hsz] = h;
        }
        gval = ngval;
        __syncthreads();
        cur ^= 1;
    }
}

// ---------------- kernel 3: final attention + FC, one WG per batch ----------------
__global__ __launch_bounds__(256) void attn_out(
    const float* __restrict__ H_all, const float* __restrict__ KV,
    const float* __restrict__ w1, const float* __restrict__ w2,
    const float* __restrict__ w_fc, const float* __restrict__ b_fc,
    float* __restrict__ out) {
    int b = blockIdx.x;
    int tid = threadIdx.x;
    __shared__ float hT[Hsz];
    __shared__ float q_s[Hsz];
    __shared__ float w2s[Hsz];
    __shared__ float s_s[Tsz];
    __shared__ float r2[2][Hsz];
    __shared__ float r_s[Hsz];

    const float* Hb = H_all + (size_t)b * Tsz * Hsz;
    const float* KVb = KV + (size_t)b * Tsz * Hsz;

    if (tid < Hsz) {
        hT[tid] = Hb[255 * Hsz + tid];
        w2s[tid] = w2[tid];
    }
    __syncthreads();
    if (tid < Hsz) {
        float acc = 0.f;
        #pragma unroll 8
        for (int k = 0; k < Hsz; ++k) acc = fmaf(hT[k], w1[k * Hsz + tid], acc);
        q_s[tid] = acc;
    }
    __syncthreads();

    const int qd = tid >> 2, ql = tid & 3;
    #pragma unroll
    for (int jj = 0; jj < 4; ++jj) {
        int j = qd + jj * 64;
        float p = 0.f;
        if (j < 255) {
            const float* kv = KVb + (size_t)j * Hsz + ql * 32;
            const float* qs = q_s + ql * 32;
            const float* wv = w2s + ql * 32;
            #pragma unroll 8
            for (int k = 0; k < 32; ++k)
                p = fmaf(tanh_s(qs[k] + kv[k]), wv[k], p);
        }
        p = quad_rsum(p);
        if (ql == 0 && j < 255) s_s[j] = p;
    }
    __syncthreads();

    {
        int dd = tid & 127, half = tid >> 7;
        int j0 = half * 128, je = half ? 255 : 128;
        float acc = 0.f;
        #pragma unroll 4
        for (int j = j0; j < je; ++j) acc = fmaf(s_s[j], Hb[(size_t)j * Hsz + dd], acc);
        r2[half][dd] = acc;
    }
    __syncthreads();
    if (tid < Hsz) r_s[tid] = hT[tid] + r2[0][tid] + r2[1][tid];
    __syncthreads();

    {
        int o = tid >> 1, half = tid & 1;
        float acc = 0.f;
        if (o < Csz) {
            const float* wr = w_fc + (size_t)o * Hsz + half * 64;
            const float* rr = r_s + half * 64;
            #pragma unroll 8
            for (int k = 0; k < 64; ++k) acc = fmaf(rr[k], wr[k], acc);
        }
        acc += __shfl_xor(acc, 1);
        if (half == 0 && o < Csz) out[b * Csz + o] = acc + b_fc[o];
    }
}

// ---------------- launch ----------------
extern "C" void kernel_launch(void* const* d_in, const int* in_sizes, int n_in,
                              void* d_out, int out_size, void* d_ws, size_t ws_size,
                              hipStream_t stream) {
    const float* x    = (const float*)d_in[0];
    const float* w_ih = (const float*)d_in[1];
    const float* b_ih = (const float*)d_in[2];
    const float* w_hh = (const float*)d_in[3];
    const float* b_hh = (const float*)d_in[4];
    const float* w1   = (const float*)d_in[5];
    const float* w2   = (const float*)d_in[6];
    const float* w_fc = (const float*)d_in[7];
    const float* b_fc = (const float*)d_in[8];

    float* ws = (float*)d_ws;
    // layout (float slots):
    float* whh_pk = ws;                              // 65536
    float* bias   = whh_pk + 65536;                  // 512
    __hip_bfloat16* W2ih = (__hip_bfloat16*)(bias + 512);        // 512*384 bf16 = 98304 f
    __hip_bfloat16* W2v  = (__hip_bfloat16*)(bias + 512 + 98304); // 128*384 bf16 = 24576 f
    __hip_bfloat16* x2   = (__hip_bfloat16*)(bias + 512 + 98304 + 24576); // 8192*256 bf16 = 1048576 f
    float* G      = bias + 512 + 98304 + 24576 + 1048576;        // 8192*512 = 4194304 f
    __hip_bfloat16* H2 = (__hip_bfloat16*)G;         // aliases G[0..1048576) after lstm
    float* KV     = G + 2097152;                     // aliases G[2097152..3145728)
    float* H_all  = G + 4194304;                     // 1048576 f
    // total = 6.48M floats ~= 25.9 MB

    prep_kernel<<<256, 256, 0, stream>>>(w_ih, b_ih, w_hh, b_hh, w1,
                                         W2ih, W2v, whh_pk, bias);

    split256<<<4096, 256, 0, stream>>>(x, x2, Bsz * Tsz * Isz);

    dim3 gG(G4H / 64, (Bsz * Tsz) / 64);             // (8, 128)
    gemm_mfma<<<gG, 256, 0, stream>>>(x2, W2ih, bias, G, Bsz * Tsz, G4H);

    lstm_seq<<<Bsz, 512, 0, stream>>>(G, whh_pk, H_all);

    split256<<<4096, 256, 0, stream>>>(H_all, H2, Bsz * Tsz * Hsz);

    dim3 gK(Hsz / 64, (Bsz * Tsz) / 64);             // (2, 128)
    gemm_mfma<<<gK, 256, 0, stream>>>(H2, W2v, nullptr, KV, Bsz * Tsz, Hsz);

    attn_out<<<Bsz, 256, 0, stream>>>(H_all, KV, w1, w2, w_fc, b_fc, (float*)d_out);
}

// Round 9
// 330.717 us; speedup vs baseline: 1.1084x; 1.0304x over previous
//
#include <hip/hip_runtime.h>
#include <hip/hip_bf16.h>

// Problem: B=32, T=256, I=128, H=128, C=100. All fp32.
// out = (h_T + attn_c_final) @ w_fc.T + b_fc; only the LAST step's attention
// matters (scan carry overwrites attn_c each step).

#define Bsz 32
#define Tsz 256
#define Isz 128
#define Hsz 128
#define Csz 100
#define G4H 512   // 4*H

typedef short v8s __attribute__((ext_vector_type(8)));   // 8 bf16 = 4 VGPRs
typedef float v4fa __attribute__((ext_vector_type(4)));  // MFMA acc

// ---------------- device helpers ----------------
__device__ __forceinline__ float2 pk_fma(float2 a, float2 b, float2 c) {
    float2 d;
    asm("v_pk_fma_f32 %0, %1, %2, %3" : "=v"(d) : "v"(a), "v"(b), "v"(c));
    return d;
}
__device__ __forceinline__ float quad_rsum(float x) {
    int t = __builtin_amdgcn_update_dpp(0, __float_as_int(x), 0xB1, 0xF, 0xF, true); // xor 1
    x += __int_as_float(t);
    t = __builtin_amdgcn_update_dpp(0, __float_as_int(x), 0x4E, 0xF, 0xF, true);     // xor 2
    x += __int_as_float(t);
    return x;
}
__device__ __forceinline__ float rcpf(float x) { return __builtin_amdgcn_rcpf(x); }
__device__ __forceinline__ float sigm_n(float x) { return rcpf(1.0f + __expf(-x)); }
__device__ __forceinline__ float tanh_n(float x) {
    float ax = fabsf(x);
    float e = __expf(-2.0f * ax);
    float t = (1.0f - e) * rcpf(1.0f + e);
    return copysignf(t, x);
}
__device__ __forceinline__ float tanh_s(float x) { return tanh_n(x); }
__device__ __forceinline__ short bf16_bits(float x) {
    __hip_bfloat16 h = __float2bfloat16(x);
    return *reinterpret_cast<short*>(&h);
}
__device__ __forceinline__ float bf16_val(float x) {
    return __bfloat162float(__float2bfloat16(x));
}

// ---------------- kernel 0: weight prep ----------------
// whh_pk: packed for lstm. bias = b_ih + b_hh. attn_c zeroed.
// W2ih[n][k'] (512 x 384 bf16): [w_hi | w_lo | w_hi]  (pairs with A=[hi|hi|lo])
// W2v [n][k'] (128 x 384 bf16): transpose-split of w1 bottom half.
__global__ __launch_bounds__(256) void prep_kernel(
    const float* __restrict__ w_ih, const float* __restrict__ b_ih,
    const float* __restrict__ w_hh, const float* __restrict__ b_hh,
    const float* __restrict__ w1,
    __hip_bfloat16* __restrict__ W2ih, __hip_bfloat16* __restrict__ W2v,
    float* __restrict__ whh_pk, float* __restrict__ bias,
    float* __restrict__ attn_c) {
    int idx = blockIdx.x * blockDim.x + threadIdx.x;   // 0..65535
    if (idx < G4H * Isz) {
        int n = idx >> 7;
        int k = idx & 127;
        float x = w_ih[idx];
        __hip_bfloat16 hi = __float2bfloat16(x);
        __hip_bfloat16 lo = __float2bfloat16(x - __bfloat162float(hi));
        W2ih[(size_t)n * 384 + k] = hi;
        W2ih[(size_t)n * 384 + 128 + k] = lo;
        W2ih[(size_t)n * 384 + 256 + k] = hi;

        int j4  = idx & 3;
        int q   = (idx >> 2) & 3;
        int d   = (idx >> 4) & 127;
        int gi  = (idx >> 11) & 3;
        int kk4 = (idx >> 13) & 7;
        whh_pk[idx] = w_hh[(size_t)((gi << 7) + d) * 128 + (q << 5) + (kk4 << 2) + j4];
    }
    if (idx < Hsz * Hsz) {
        int n = idx >> 7;          // output col of KV
        int k = idx & 127;
        float x = w1[(size_t)(128 + k) * Hsz + n];
        __hip_bfloat16 hi = __float2bfloat16(x);
        __hip_bfloat16 lo = __float2bfloat16(x - __bfloat162float(hi));
        W2v[(size_t)n * 384 + k] = hi;
        W2v[(size_t)n * 384 + 128 + k] = lo;
        W2v[(size_t)n * 384 + 256 + k] = hi;
    }
    if (idx < G4H) bias[idx] = b_ih[idx] + b_hh[idx];
    if (idx < Bsz * Hsz) attn_c[idx] = 0.0f;
}

// ---------------- gemm_mfma_f32a: C[M,N] = split(A_fp32) @ split(W)^T (+bias) ----
// A: [M][128] fp32, converted in-register to hi/lo bf16 (split256 fused away).
// W2: [N][384] bf16 = [w_hi | w_lo | w_hi]. 12 k-steps of 32:
// ks 0-3: A_hi*W_hi, 4-7: A_hi*W_lo, 8-11: A_lo*W_hi  (~2^-17 rel err).
// 256 thr = 4 waves; each wave one 32x32 C tile (2x2 16x16x32 MFMA frags).
__global__ __launch_bounds__(256) void gemm_mfma_f32a(
    const float* __restrict__ A, const __hip_bfloat16* __restrict__ W2,
    const float* __restrict__ bias, float* __restrict__ C, int M, int N) {
    const int tid = threadIdx.x;
    const int w = tid >> 6, lane = tid & 63;
    const int m0 = blockIdx.y * 64 + (w & 1) * 32;
    const int n0 = blockIdx.x * 64 + (w >> 1) * 32;
    const int r = lane & 15, quad = lane >> 4;

    // preload + convert this thread's A fragments once (reused 2x for hi)
    v8s Ahi[2][4], Alo[2][4];
    #pragma unroll
    for (int i = 0; i < 2; ++i)
        #pragma unroll
        for (int cb = 0; cb < 4; ++cb) {
            const float* src = A + (size_t)(m0 + 16 * i + r) * Isz + cb * 32 + quad * 8;
            float4 f0 = *(const float4*)src;
            float4 f1 = *(const float4*)(src + 4);
            float f[8] = {f0.x, f0.y, f0.z, f0.w, f1.x, f1.y, f1.z, f1.w};
            v8s hi, lo;
            #pragma unroll
            for (int e = 0; e < 8; ++e) {
                float hv = bf16_val(f[e]);
                hi[e] = bf16_bits(f[e]);
                lo[e] = bf16_bits(f[e] - hv);
            }
            Ahi[i][cb] = hi;
            Alo[i][cb] = lo;
        }

    v4fa acc[2][2] = {};
    const short* Wb = (const short*)W2;
    #pragma unroll
    for (int ks = 0; ks < 12; ++ks) {
        int cb = ks & 3;
        v8s a0 = (ks >= 8) ? Alo[0][cb] : Ahi[0][cb];
        v8s a1 = (ks >= 8) ? Alo[1][cb] : Ahi[1][cb];
        int kb = ks * 32 + quad * 8;
        v8s b0 = *(const v8s*)(Wb + (size_t)(n0 + r) * 384 + kb);
        v8s b1 = *(const v8s*)(Wb + (size_t)(n0 + 16 + r) * 384 + kb);
        acc[0][0] = __builtin_amdgcn_mfma_f32_16x16x32_bf16(a0, b0, acc[0][0], 0, 0, 0);
        acc[0][1] = __builtin_amdgcn_mfma_f32_16x16x32_bf16(a0, b1, acc[0][1], 0, 0, 0);
        acc[1][0] = __builtin_amdgcn_mfma_f32_16x16x32_bf16(a1, b0, acc[1][0], 0, 0, 0);
        acc[1][1] = __builtin_amdgcn_mfma_f32_16x16x32_bf16(a1, b1, acc[1][1], 0, 0, 0);
    }
    // C/D layout: col = lane&15, row = quad*4 + reg  [verified m89/m91]
    #pragma unroll
    for (int i = 0; i < 2; ++i)
        #pragma unroll
        for (int j = 0; j < 2; ++j) {
            int cn = n0 + 16 * j + r;
            float bb = bias ? bias[cn] : 0.0f;
            #pragma unroll
            for (int rr = 0; rr < 4; ++rr) {
                int row = m0 + 16 * i + quad * 4 + rr;
                C[(size_t)row * N + cn] = acc[i][j][rr] + bb;
            }
        }
}

// ---------------- kernel 2: sequential LSTM (plateau structure, do not touch) ----
#define HPAD(k) ((k) + 8 * ((k) >> 5))

__global__ __launch_bounds__(512, 2) void lstm_seq(
    const float* __restrict__ G, const float* __restrict__ whh_pk,
    float* __restrict__ H_all) {
    const int b = blockIdx.x;
    const int tid = threadIdx.x;
    const int d = tid >> 2;
    const int q = tid & 3;

    __shared__ float h_s[2][160];

    float2 w2v[4][16];
    {
        const float4* wp = (const float4*)whh_pk;
        #pragma unroll
        for (int kk4 = 0; kk4 < 8; ++kk4)
            #pragma unroll
            for (int gi = 0; gi < 4; ++gi) {
                float4 v = wp[((kk4 * 4 + gi) * 128 + d) * 4 + q];
                w2v[gi][kk4 * 2]     = make_float2(v.x, v.y);
                w2v[gi][kk4 * 2 + 1] = make_float2(v.z, v.w);
            }
    }

    if (tid < 320) ((float*)h_s)[tid] = 0.0f;
    float c = 0.0f;
    __syncthreads();

    const float* Gq = G + (size_t)b * Tsz * G4H + q * 128 + d;
    float* Hst = H_all + (size_t)b * Tsz * Hsz + d;

    float gval = Gq[0];
    int cur = 0;
    for (int t = 0; t < Tsz; ++t) {
        const int tn = (t < Tsz - 1) ? t + 1 : t;
        float ngval = Gq[(size_t)tn * G4H];   // prefetch, independent of h

        float2 accA[4], accB[4];
        #pragma unroll
        for (int gi = 0; gi < 4; ++gi) {
            accA[gi] = make_float2(q == gi ? gval : 0.f, 0.f);
            accB[gi] = make_float2(0.f, 0.f);
        }
        const float4* hb4 = (const float4*)&h_s[cur][q * 40];  // HPAD(q*32)=q*40
        #pragma unroll
        for (int kk4 = 0; kk4 < 8; ++kk4) {
            float4 h4 = hb4[kk4];
            float2 hA = make_float2(h4.x, h4.y);
            float2 hB = make_float2(h4.z, h4.w);
            accA[0] = pk_fma(hA, w2v[0][2 * kk4], accA[0]);
            accA[1] = pk_fma(hA, w2v[1][2 * kk4], accA[1]);
            accA[2] = pk_fma(hA, w2v[2][2 * kk4], accA[2]);
            accA[3] = pk_fma(hA, w2v[3][2 * kk4], accA[3]);
            accB[0] = pk_fma(hB, w2v[0][2 * kk4 + 1], accB[0]);
            accB[1] = pk_fma(hB, w2v[1][2 * kk4 + 1], accB[1]);
            accB[2] = pk_fma(hB, w2v[2][2 * kk4 + 1], accB[2]);
            accB[3] = pk_fma(hB, w2v[3][2 * kk4 + 1], accB[3]);
        }
        float a0 = quad_rsum(accA[0].x + accA[0].y + accB[0].x + accB[0].y);
        float a1 = quad_rsum(accA[1].x + accA[1].y + accB[1].x + accB[1].y);
        float a2 = quad_rsum(accA[2].x + accA[2].y + accB[2].x + accB[2].y);
        float a3 = quad_rsum(accA[3].x + accA[3].y + accB[3].x + accB[3].y);

        float iv = sigm_n(a0);
        float fv = sigm_n(a1);
        float gv = tanh_n(a2);
        float ov = sigm_n(a3);
        c = fv * c + iv * gv;
        float h = ov * tanh_n(c);

        if (q == 0) {
            h_s[cur ^ 1][HPAD(d)] = h;
            Hst[(size_t)t * Hsz] = h;
        }
        gval = ngval;
        __syncthreads();
        cur ^= 1;
    }
}

// ---------------- kernel 3a: scores + partial attn_c, grid (4 jt, 32 b) ----------------
// Each block: recompute q (cheap), score 64 memory slots, partial
// attn_c over those slots, one atomicAdd per (b,d).
__global__ __launch_bounds__(256) void scores_part(
    const float* __restrict__ H_all, const float* __restrict__ KV,
    const float* __restrict__ w1, const float* __restrict__ w2,
    float* __restrict__ attn_c) {
    const int b = blockIdx.y, jt = blockIdx.x;
    const int tid = threadIdx.x;
    __shared__ float hT[Hsz];
    __shared__ float q_s[Hsz];
    __shared__ float w2s[Hsz];
    __shared__ float s_s[64];
    __shared__ float part[2][Hsz];

    const float* Hb = H_all + (size_t)b * Tsz * Hsz;
    const float* KVb = KV + (size_t)b * Tsz * Hsz;

    if (tid < Hsz) {
        hT[tid] = Hb[255 * Hsz + tid];
        w2s[tid] = w2[tid];
    }
    __syncthreads();
    if (tid < Hsz) {
        float acc = 0.f;
        #pragma unroll 8
        for (int k = 0; k < Hsz; ++k) acc = fmaf(hT[k], w1[k * Hsz + tid], acc);
        q_s[tid] = acc;
    }
    __syncthreads();

    // one quad per j (64 j's per block)
    const int jl = tid >> 2, ql = tid & 3;
    const int j = jt * 64 + jl;
    float p = 0.f;
    if (j < 255) {
        const float* kv = KVb + (size_t)j * Hsz + ql * 32;
        const float* qs = q_s + ql * 32;
        const float* wv = w2s + ql * 32;
        #pragma unroll 8
        for (int k = 0; k < 32; ++k)
            p = fmaf(tanh_s(qs[k] + kv[k]), wv[k], p);
    }
    p = quad_rsum(p);
    if (ql == 0) s_s[jl] = (j < 255) ? p : 0.0f;
    __syncthreads();

    // partial attn_c over this block's 64 slots (two 32-slot halves)
    {
        const int dd = tid & 127, half = tid >> 7;
        float acc = 0.f;
        #pragma unroll 4
        for (int u = 0; u < 32; ++u) {
            int lj = half * 32 + u;
            int jj = jt * 64 + lj;
            if (jj < 255) acc = fmaf(s_s[lj], Hb[(size_t)jj * Hsz + dd], acc);
        }
        part[half][dd] = acc;
    }
    __syncthreads();
    if (tid < Hsz) atomicAdd(&attn_c[b * Hsz + tid], part[0][tid] + part[1][tid]);
}

// ---------------- kernel 3b: final FC ----------------
__global__ __launch_bounds__(256) void fc_out(
    const float* __restrict__ H_all, const float* __restrict__ attn_c,
    const float* __restrict__ w_fc, const float* __restrict__ b_fc,
    float* __restrict__ out) {
    const int b = blockIdx.x, tid = threadIdx.x;
    __shared__ float r_s[Hsz];
    if (tid < Hsz)
        r_s[tid] = H_all[(size_t)b * Tsz * Hsz + 255 * Hsz + tid] + attn_c[b * Hsz + tid];
    __syncthreads();
    const int o = tid >> 1, half = tid & 1;
    float acc = 0.f;
    if (o < Csz) {
        const float* wr = w_fc + (size_t)o * Hsz + half * 64;
        const float* rr = r_s + half * 64;
        #pragma unroll 8
        for (int k = 0; k < 64; ++k) acc = fmaf(rr[k], wr[k], acc);
    }
    acc += __shfl_xor(acc, 1);
    if (half == 0 && o < Csz) out[b * Csz + o] = acc + b_fc[o];
}

// ---------------- launch ----------------
extern "C" void kernel_launch(void* const* d_in, const int* in_sizes, int n_in,
                              void* d_out, int out_size, void* d_ws, size_t ws_size,
                              hipStream_t stream) {
    const float* x    = (const float*)d_in[0];
    const float* w_ih = (const float*)d_in[1];
    const float* b_ih = (const float*)d_in[2];
    const float* w_hh = (const float*)d_in[3];
    const float* b_hh = (const float*)d_in[4];
    const float* w1   = (const float*)d_in[5];
    const float* w2   = (const float*)d_in[6];
    const float* w_fc = (const float*)d_in[7];
    const float* b_fc = (const float*)d_in[8];

    float* ws = (float*)d_ws;
    float* whh_pk = ws;                               // 65536
    float* bias   = whh_pk + 65536;                   // 512
    float* attn_c = bias + 512;                       // 4096
    __hip_bfloat16* W2ih = (__hip_bfloat16*)(attn_c + 4096);       // 98304 f
    __hip_bfloat16* W2v  = (__hip_bfloat16*)(attn_c + 4096 + 98304); // 24576 f
    float* G      = attn_c + 4096 + 98304 + 24576;    // 8192*512 = 4194304 f
    float* H_all  = G + 4194304;                      // 1048576 f
    float* KV     = H_all + 1048576;                  // 1048576 f
    // total ~6.44M floats ~= 25.8 MB

    prep_kernel<<<256, 256, 0, stream>>>(w_ih, b_ih, w_hh, b_hh, w1,
                                         W2ih, W2v, whh_pk, bias, attn_c);

    dim3 gG(G4H / 64, (Bsz * Tsz) / 64);              // (8, 128)
    gemm_mfma_f32a<<<gG, 256, 0, stream>>>(x, W2ih, bias, G, Bsz * Tsz, G4H);

    lstm_seq<<<Bsz, 512, 0, stream>>>(G, whh_pk, H_all);

    dim3 gK(Hsz / 64, (Bsz * Tsz) / 64);              // (2, 128)
    gemm_mfma_f32a<<<gK, 256, 0, stream>>>(H_all, W2v, nullptr, KV, Bsz * Tsz, Hsz);

    dim3 gS(4, Bsz);                                  // (4 jt, 32 b)
    scores_part<<<gS, 256, 0, stream>>>(H_all, KV, w1, w2, attn_c);

    fc_out<<<Bsz, 256, 0, stream>>>(H_all, attn_c, w_fc, b_fc, (float*)d_out);
}